// Round 10
// baseline (348.187 us; speedup 1.0000x reference)
//
#include <hip/hip_runtime.h>
#include <math.h>

#define M_ROWS 32768
#define N_CLS  2048
#define NGRP   8
#define CPG    256
#define NS     10
#define NCAND  16
#define EDIM   400
#define KPAD   416            // 13 * 32, zero-padded
#define NKT    13
#define BK     32
#define SGS    448            // padded group-sum stride (>= lane+384 max 447)
#define NPART  32             // d~ partial sums per row (16 n-tiles x 2 wave-halves)

typedef _Float16 f16x8 __attribute__((ext_vector_type(8)));
typedef float f32x4 __attribute__((ext_vector_type(4)));

__device__ __forceinline__ void gld_lds16(const void* g, void* l) {
    __builtin_amdgcn_global_load_lds(
        (const __attribute__((address_space(1))) unsigned int*)g,
        (__attribute__((address_space(3))) unsigned int*)l, 16, 0, 0);
}

// ---- DPP cross-lane helpers (VALU pipe, no DS)
#define DPP_X1 0xB1
#define DPP_X2 0x4E
#define DPP_X8 0x128

template <int CTRL>
__device__ __forceinline__ int dpp_i(int v) {
    return __builtin_amdgcn_update_dpp(v, v, CTRL, 0xF, 0xF, true);
}
template <int CTRL>
__device__ __forceinline__ float dpp_f(float v) {
    return __builtin_bit_cast(float,
        __builtin_amdgcn_update_dpp(__builtin_bit_cast(int, v),
                                    __builtin_bit_cast(int, v), CTRL, 0xF, 0xF, true));
}
template <int J>
__device__ __forceinline__ float xch_f(float v) {
    if constexpr (J == 1) return dpp_f<DPP_X1>(v);
    else if constexpr (J == 2) return dpp_f<DPP_X2>(v);
    else if constexpr (J == 8) return dpp_f<DPP_X8>(v);
    else return __shfl_xor(v, J, 64);
}
template <int J>
__device__ __forceinline__ int xch_i(int v) {
    if constexpr (J == 1) return dpp_i<DPP_X1>(v);
    else if constexpr (J == 2) return dpp_i<DPP_X2>(v);
    else if constexpr (J == 8) return dpp_i<DPP_X8>(v);
    else return __shfl_xor(v, J, 64);
}

// ---------------- fp32 -> f16 hi (K padded to 416) + row sum-of-squares ----------------
__global__ __launch_bounds__(256) void k_split_hi(const float* __restrict__ in,
                                                  unsigned short* __restrict__ hi,
                                                  float* __restrict__ ss, int rows) {
    int row  = blockIdx.x * 4 + (threadIdx.x >> 6);
    int lane = threadIdx.x & 63;
    if (row >= rows) return;
    const float* src = in + (size_t)row * EDIM;
    unsigned short* ph = hi + (size_t)row * KPAD;
    float s = 0.f;
    #pragma unroll
    for (int q = 0; q < 2; ++q) {
        int c4 = lane + q * 64;
        if (c4 < KPAD / 4) {
            int k = c4 * 4;
            float4 v = make_float4(0.f, 0.f, 0.f, 0.f);
            if (k < EDIM) v = *(const float4*)(src + k);
            float va[4] = {v.x, v.y, v.z, v.w};
            unsigned short ha[4];
            #pragma unroll
            for (int t = 0; t < 4; ++t) {
                float f = va[t];
                _Float16 h = (_Float16)f;
                ha[t] = __builtin_bit_cast(unsigned short, h);
                s = fmaf(f, f, s);
            }
            ushort4 H; H.x = ha[0]; H.y = ha[1]; H.z = ha[2]; H.w = ha[3];
            *(ushort4*)(ph + k) = H;
        }
    }
    #pragma unroll
    for (int o = 32; o; o >>= 1) s += __shfl_xor(s, o, 64);
    if (lane == 0) ss[row] = s;
}

// ---------------- per-group embedding sums: Sg = sum emb (exact), SgH = sum fl16(emb) ----------------
__global__ __launch_bounds__(448) void k_groupsum(const float* __restrict__ emb,
                                                  const unsigned short* __restrict__ ehi,
                                                  float* __restrict__ Sg,
                                                  float* __restrict__ SgH) {
    const int g = blockIdx.x;
    const int t = threadIdx.x;          // 0..447
    float se = 0.f, sh = 0.f;
    if (t < EDIM) {
        for (int j = 0; j < CPG; ++j) {
            se += emb[(size_t)(g * CPG + j) * EDIM + t];
            _Float16 h = __builtin_bit_cast(_Float16, ehi[(size_t)(g * CPG + j) * KPAD + t]);
            sh += (float)h;
        }
    }
    Sg[g * SGS + t]  = se;
    SgH[g * SGS + t] = sh;
}

// ---------------- 1-pass f16 MFMA distance GEMM, 2-phase pipelined ----------------
// Race lessons (R7, R9):
//  * raw s_barrier is not a compiler fence -> all sync points are single asm
//    blocks with "memory" clobber (R7 fix: stage() can't hoist above them).
//  * s_barrier is not an LDS-read completion point either: a wave can pass it
//    with ds_reads still in flight (the compiler attaches lgkmcnt waits to the
//    MFMA consumers, which may sink below the barrier — rule #18/#19). The end
//    barrier therefore carries s_waitcnt lgkmcnt(0): reads complete into regs
//    BEFORE the wave passes; the next iteration may then safely overwrite the
//    buffer no matter where the MFMAs were scheduled. (R9's post-timing
//    divergence was this hazard, exposed by codegen perturbation.)
__global__ __launch_bounds__(256, 4) void k_dist1(
    const unsigned short* __restrict__ xhi, const unsigned short* __restrict__ ehi,
    const float* __restrict__ xx, const float* __restrict__ ee,
    float* __restrict__ enc, float* __restrict__ gsum) {
    __shared__ __attribute__((aligned(16))) _Float16 Ah[2][128][BK];
    __shared__ __attribute__((aligned(16))) _Float16 Bh[2][128][BK];

    const int wg    = blockIdx.x;
    const int xcd   = wg & 7;
    const int local = wg >> 3;            // 0..511
    const int mx    = xcd * 32 + (local & 31);
    const int ny    = local >> 5;         // 0..15
    const int m0    = mx * 128;
    const int n0    = ny * 128;

    const int tid  = threadIdx.x;
    const int lane = tid & 63, wid = tid >> 6;
    const int wr = (wid >> 1) * 64, wc = (wid & 1) * 64;
    const int lr = lane & 15, ko = lane >> 4;

    auto stage = [&](int b, int kt) {
        const int k0 = kt * BK;
        #pragma unroll
        for (int q = 0; q < 2; ++q) {
            int cc = q * 256 + tid;       // 0..511 chunks of 16B per array
            int rw = cc >> 2, kc = cc & 3;
            size_t goA = (size_t)(m0 + rw) * KPAD + k0 + kc * 8;
            size_t goB = (size_t)(n0 + rw) * KPAD + k0 + kc * 8;
            int loff = (cc >> 6) * 1024;  // wave-uniform LDS base
            gld_lds16(xhi + goA, (char*)&Ah[b][0][0] + loff);
            gld_lds16(ehi + goB, (char*)&Bh[b][0][0] + loff);
        }
    };

    f32x4 acc[4][4];
    #pragma unroll
    for (int i = 0; i < 4; ++i)
        #pragma unroll
        for (int j = 0; j < 4; ++j) { f32x4 z = {0.f, 0.f, 0.f, 0.f}; acc[i][j] = z; }

    stage(0, 0);
    for (int kt = 0; kt < NKT; ++kt) {
        const int cur = kt & 1;
        if (kt + 1 < NKT) {
            stage(cur ^ 1, kt + 1);       // next tile's 4 loads in flight
            // own current-tile loads landed (vmcnt(4)) + join all waves
            asm volatile("s_waitcnt vmcnt(4)\n\ts_barrier" ::: "memory");
        } else {
            asm volatile("s_waitcnt vmcnt(0)\n\ts_barrier" ::: "memory");
        }

        f16x8 a_h[4];
        #pragma unroll
        for (int i = 0; i < 4; ++i)
            a_h[i] = *(const f16x8*)&Ah[cur][wr + i * 16 + lr][ko * 8];
        #pragma unroll
        for (int j = 0; j < 4; ++j) {
            f16x8 b_h = *(const f16x8*)&Bh[cur][wc + j * 16 + lr][ko * 8];
            #pragma unroll
            for (int i = 0; i < 4; ++i)
                acc[i][j] = __builtin_amdgcn_mfma_f32_16x16x32_f16(a_h[i], b_h, acc[i][j], 0, 0, 0);
        }
        // LDS reads COMPLETE (lgkmcnt(0)) before this wave passes; then barrier.
        asm volatile("s_waitcnt lgkmcnt(0)\n\ts_barrier" ::: "memory");
    }

    #pragma unroll
    for (int i = 0; i < 4; ++i) {
        #pragma unroll
        for (int r = 0; r < 4; ++r) {
            int row = m0 + wr + i * 16 + ko * 4 + r;
            float xm = xx[row];
            float rs = 0.f;
            #pragma unroll
            for (int j = 0; j < 4; ++j) {
                int col = n0 + wc + j * 16 + lr;
                float dd = fmaf(-2.f, acc[i][j][r], xm + ee[col]);
                rs += dd;
                enc[(size_t)row * N_CLS + col] = 1.0f / dd;
            }
            rs += dpp_f<DPP_X1>(rs);
            rs += dpp_f<DPP_X2>(rs);
            rs += __shfl_xor(rs, 4, 64);
            rs += dpp_f<DPP_X8>(rs);
            if (lr == 0)
                gsum[(size_t)row * NPART + ny * 2 + (wc >> 6)] = rs;
        }
    }
}

// ---------------- per-row select: DPP-ified (R8-passing version, unchanged) ----------------
__global__ __launch_bounds__(256) void k_select5(const float* __restrict__ x,
                                                 const float* __restrict__ emb,
                                                 const float* __restrict__ enc,
                                                 const float* __restrict__ gsum,
                                                 const float* __restrict__ Sg,
                                                 const float* __restrict__ SgH,
                                                 const float* __restrict__ xx,
                                                 const float* __restrict__ ee,
                                                 float* __restrict__ out0,
                                                 float* __restrict__ rmse,
                                                 unsigned int* __restrict__ hist) {
    const int wave = threadIdx.x >> 6;
    const int lane = threadIdx.x & 63;
    const int m = blockIdx.x * 4 + wave;

    const float* xrg = x + (size_t)m * EDIM;
    float xr[7], xh[7];
    #pragma unroll
    for (int k = 0; k < 7; ++k) {
        int d = lane + 64 * k;
        float f = (d < EDIM) ? xrg[d] : 0.f;
        xr[k] = f;
        xh[k] = (float)(_Float16)f;
    }
    const float xm = xx[m];

    // ---- group scores: d~ partial sums + exact correction -2*(x.Sg - x_hi.SgH) ----
    float aD[NGRP];
    #pragma unroll
    for (int g = 0; g < NGRP; ++g) aD[g] = 0.f;
    #pragma unroll
    for (int k = 0; k < 7; ++k) {
        int d = lane + 64 * k;   // < 448 always; pads are zero
        #pragma unroll
        for (int g = 0; g < NGRP; ++g) {
            aD[g] = fmaf(xr[k], Sg[g * SGS + d], aD[g]);
            aD[g] = fmaf(-xh[k], SgH[g * SGS + d], aD[g]);
        }
    }
    // class-reduce (xor 8,16,32): lane l -> partial over lanes == l (mod 8)
    #pragma unroll
    for (int g = 0; g < NGRP; ++g) {
        aD[g] += dpp_f<DPP_X8>(aD[g]);
        aD[g] += __shfl_xor(aD[g], 16, 64);
        aD[g] += __shfl_xor(aD[g], 32, 64);
    }
    const int myg = (lane >> 3) & 7;
    float s = aD[0];
    s = (myg == 1) ? aD[1] : s;
    s = (myg == 2) ? aD[2] : s;
    s = (myg == 3) ? aD[3] : s;
    s = (myg == 4) ? aD[4] : s;
    s = (myg == 5) ? aD[5] : s;
    s = (myg == 6) ? aD[6] : s;
    s = (myg == 7) ? aD[7] : s;
    s += dpp_f<DPP_X1>(s);
    s += dpp_f<DPP_X2>(s);
    s += __shfl_xor(s, 4, 64);
    const float* gs = gsum + (size_t)m * NPART;
    float base = gs[myg * 4 + 0] + gs[myg * 4 + 1] + gs[myg * 4 + 2] + gs[myg * 4 + 3];
    float sc = fmaf(-2.f, s, base);
    // 8-way argmin (ties -> lowest g) over the group-holder bits (xor 8,16,32)
    int bg = myg; float bv = sc;
    {
        float ov = dpp_f<DPP_X8>(bv); int og = dpp_i<DPP_X8>(bg);
        if (ov < bv || (ov == bv && og < bg)) { bv = ov; bg = og; }
    }
    #pragma unroll
    for (int o = 16; o < 64; o <<= 1) {
        float ov = __shfl_xor(bv, o, 64);
        int   og = __shfl_xor(bg, o, 64);
        if (ov < bv || (ov == bv && og < bg)) { bv = ov; bg = og; }
    }
    const int j0 = bg * CPG;

    // ---- Phase A: top-16 candidates via packed u32 keys (val | inverted idx) ----
    const float* pr = enc + (size_t)m * N_CLS + j0;
    float4 pv4 = *(const float4*)(pr + lane * 4);
    unsigned key0 = (__float_as_uint(pv4.x) & 0xFFFFFF00u) | (255u - (unsigned)(lane * 4 + 0));
    unsigned key1 = (__float_as_uint(pv4.y) & 0xFFFFFF00u) | (255u - (unsigned)(lane * 4 + 1));
    unsigned key2 = (__float_as_uint(pv4.z) & 0xFFFFFF00u) | (255u - (unsigned)(lane * 4 + 2));
    unsigned key3 = (__float_as_uint(pv4.w) & 0xFFFFFF00u) | (255u - (unsigned)(lane * 4 + 3));

    unsigned candKey = 0;
    #pragma unroll
    for (int t = 0; t < NCAND; ++t) {
        unsigned a01 = key0 > key1 ? key0 : key1;
        unsigned a23 = key2 > key3 ? key2 : key3;
        unsigned mk  = a01 > a23 ? a01 : a23;
        { unsigned o = (unsigned)dpp_i<DPP_X1>((int)mk); mk = o > mk ? o : mk; }
        { unsigned o = (unsigned)dpp_i<DPP_X2>((int)mk); mk = o > mk ? o : mk; }
        { unsigned o = (unsigned)__shfl_xor((int)mk, 4, 64); mk = o > mk ? o : mk; }
        { unsigned o = (unsigned)dpp_i<DPP_X8>((int)mk); mk = o > mk ? o : mk; }
        { unsigned o = (unsigned)__shfl_xor((int)mk, 16, 64); mk = o > mk ? o : mk; }
        { unsigned o = (unsigned)__shfl_xor((int)mk, 32, 64); mk = o > mk ? o : mk; }
        if (lane == t) candKey = mk;
        unsigned widx = 255u - (mk & 0xFFu);
        if ((widx >> 2) == (unsigned)lane) {
            unsigned slot = widx & 3u;
            key0 = (slot == 0u) ? 0u : key0;
            key1 = (slot == 1u) ? 0u : key1;
            key2 = (slot == 2u) ? 0u : key2;
            key3 = (slot == 3u) ? 0u : key3;
        }
    }
    int cand = 255 - (int)(candKey & 0xFFu);   // valid on lanes 0..15

    // ---- Phase B: exact fp32 refine, 4 lanes per candidate ----
    int cj = __shfl(cand, lane >> 2, 64);
    int jg = j0 + cj;
    const float4* er4 = (const float4*)(emb + (size_t)jg * EDIM);
    const float4* xs4 = (const float4*)xrg;
    float a = 0.f;
    #pragma unroll
    for (int q = 0; q < 25; ++q) {
        int idx = (lane & 3) + 4 * q;              // 0..99
        float4 e = er4[idx];
        float4 xv = xs4[idx];
        a = fmaf(xv.x, e.x, a);
        a = fmaf(xv.y, e.y, a);
        a = fmaf(xv.z, e.z, a);
        a = fmaf(xv.w, e.w, a);
    }
    a += dpp_f<DPP_X1>(a);
    a += dpp_f<DPP_X2>(a);
    float dd = fmaf(-2.f, a, xm + ee[jg]);
    float pvq = 1.0f / dd;
    // replicate the 16 refined (val, idx) pairs into every 16-lane group
    float pcur = __shfl(pvq, (lane & 15) * 4, 64);
    int   ccur = __shfl(cand, lane & 15, 64);

    // ---- Phase C: bitonic sort-16 desc by (pv, -cidx); lane t -> t-th ranked ----
    const int l16 = lane & 15;
#define BSTEP(K_, J_) { \
        float opv = xch_f<J_>(pcur); int occ = xch_i<J_>(ccur); \
        bool amLow     = (l16 & (J_)) == 0; \
        bool blockDesc = (l16 & (K_)) == 0; \
        bool iGreater  = (pcur > opv) || (pcur == opv && ccur < occ); \
        bool keep = (amLow == blockDesc) ? iGreater : !iGreater; \
        if (!keep) { pcur = opv; ccur = occ; } }
    BSTEP(2, 1)
    BSTEP(4, 2) BSTEP(4, 1)
    BSTEP(8, 4) BSTEP(8, 2) BSTEP(8, 1)
    BSTEP(16, 8) BSTEP(16, 4) BSTEP(16, 2) BSTEP(16, 1)
#undef BSTEP

    // L1 norm over the 10 winners (all values positive)
    float ps = (l16 < NS) ? pcur : 0.f;
    ps += dpp_f<DPP_X1>(ps);
    ps += dpp_f<DPP_X2>(ps);
    ps += __shfl_xor(ps, 4, 64);
    ps += dpp_f<DPP_X8>(ps);
    float wn = fmaxf(ps, 1e-12f);

    if (lane == 0) atomicAdd(&hist[j0 + ccur], 1u);   // lane 0 = top-1

    // ---- Phase D: weighted gather-sum + straight-through + mse ----
    float wt[NS]; int gt[NS];
    #pragma unroll
    for (int t = 0; t < NS; ++t) {
        wt[t] = __shfl(pcur, t, 16) / wn;
        gt[t] = j0 + __shfl(ccur, t, 16);
    }
    float* orow = out0 + (size_t)m * EDIM;
    float sq = 0.f;
    #pragma unroll
    for (int k = 0; k < 7; ++k) {
        int d = lane + 64 * k;
        if (d < EDIM) {
            float o = 0.f;
            #pragma unroll
            for (int t = 0; t < NS; ++t) o = fmaf(wt[t], emb[(size_t)gt[t] * EDIM + d], o);
            float xv = xr[k];
            float diff = xv - o;
            sq = fmaf(diff, diff, sq);
            orow[d] = (o - xv) + xv;
        }
    }
    sq += dpp_f<DPP_X1>(sq);
    sq += dpp_f<DPP_X2>(sq);
    sq += __shfl_xor(sq, 4, 64);
    sq += dpp_f<DPP_X8>(sq);
    sq += __shfl_xor(sq, 16, 64);
    sq += __shfl_xor(sq, 32, 64);
    if (lane == 0) rmse[m] = sq;
}

// ---------------- final deterministic reduction: loss + entropy ----------------
__global__ __launch_bounds__(1024) void k_final(const float* __restrict__ rmse,
                                                const unsigned int* __restrict__ hist,
                                                float* __restrict__ loss_out,
                                                float* __restrict__ ent_out) {
    __shared__ float red[1024];
    const int t = threadIdx.x;

    float s = 0.f;
    for (int i = t; i < M_ROWS; i += 1024) s += rmse[i];
    red[t] = s; __syncthreads();
    for (int off = 512; off; off >>= 1) {
        if (t < off) red[t] += red[t + off];
        __syncthreads();
    }
    if (t == 0) {
        float q = red[0] / 13107200.0f;
        loss_out[0] = q + 0.25f * q;
    }
    __syncthreads();

    float e = 0.f;
    for (int i = t; i < N_CLS; i += 1024) {
        unsigned int h = hist[i];
        if (h > 0) {
            float prb = (float)h / 32768.0f;
            e -= prb * logf(prb);
        }
    }
    red[t] = e; __syncthreads();
    for (int off = 512; off; off >>= 1) {
        if (t < off) red[t] += red[t + off];
        __syncthreads();
    }
    if (t == 0) ent_out[0] = red[0];
}

extern "C" void kernel_launch(void* const* d_in, const int* in_sizes, int n_in,
                              void* d_out, int out_size, void* d_ws, size_t ws_size,
                              hipStream_t stream) {
    const float* x   = (const float*)d_in[0];   // [32768, 400]
    const float* emb = (const float*)d_in[1];   // [2048, 400]

    float* out      = (float*)d_out;
    float* loss_out = out;
    float* out0     = out + 1;
    float* ent_out  = out + 1 + M_ROWS * EDIM;
    float* enc      = out + 2 + M_ROWS * EDIM;

    float* ws   = (float*)d_ws;
    float* ee   = ws;                                   // [2048]
    float* xx   = ee + N_CLS;                           // [32768]
    float* Sg   = xx + M_ROWS;                          // [8][448]
    float* SgH  = Sg + NGRP * SGS;                      // [8][448]
    float* gsum = SgH + NGRP * SGS;                     // [32768][32]
    float* rmse = gsum + (size_t)M_ROWS * NPART;        // [32768]
    unsigned int* hist = (unsigned int*)(rmse + M_ROWS);// [2048]
    float* fend = rmse + M_ROWS + N_CLS;

    unsigned short* xhi = (unsigned short*)fend;        // [32768][416]
    unsigned short* ehi = xhi + (size_t)M_ROWS * KPAD;  // [2048][416]

    hipMemsetAsync(hist, 0, N_CLS * sizeof(unsigned int), stream);

    k_split_hi<<<M_ROWS / 4, 256, 0, stream>>>(x, xhi, xx, M_ROWS);
    k_split_hi<<<N_CLS / 4, 256, 0, stream>>>(emb, ehi, ee, N_CLS);
    k_groupsum<<<NGRP, 448, 0, stream>>>(emb, ehi, Sg, SgH);

    k_dist1<<<(M_ROWS / 128) * (N_CLS / 128), 256, 0, stream>>>(xhi, ehi, xx, ee, enc, gsum);

    k_select5<<<M_ROWS / 4, 256, 0, stream>>>(x, emb, enc, gsum, Sg, SgH, xx, ee,
                                              out0, rmse, hist);

    k_final<<<1, 1024, 0, stream>>>(rmse, hist, loss_out, ent_out);
}

// Round 11
// 336.769 us; speedup vs baseline: 1.0339x; 1.0339x over previous
//
#include <hip/hip_runtime.h>
#include <math.h>

#define M_ROWS 32768
#define N_CLS  2048
#define NGRP   8
#define CPG    256
#define NS     10
#define NCAND  16
#define EDIM   400
#define KPAD   416            // 13 * 32, zero-padded
#define NKT    13
#define BK     32
#define SGS    448            // padded group-sum stride (>= lane+384 max 447)
#define NPART  32             // d~ partial sums per row (16 n-tiles x 2 wave-halves)

typedef _Float16 f16x8 __attribute__((ext_vector_type(8)));
typedef float f32x4 __attribute__((ext_vector_type(4)));

__device__ __forceinline__ void gld_lds16(const void* g, void* l) {
    __builtin_amdgcn_global_load_lds(
        (const __attribute__((address_space(1))) unsigned int*)g,
        (__attribute__((address_space(3))) unsigned int*)l, 16, 0, 0);
}

// ---- DPP cross-lane helpers (VALU pipe, no DS)
#define DPP_X1 0xB1
#define DPP_X2 0x4E
#define DPP_X8 0x128

template <int CTRL>
__device__ __forceinline__ int dpp_i(int v) {
    return __builtin_amdgcn_update_dpp(v, v, CTRL, 0xF, 0xF, true);
}
template <int CTRL>
__device__ __forceinline__ float dpp_f(float v) {
    return __builtin_bit_cast(float,
        __builtin_amdgcn_update_dpp(__builtin_bit_cast(int, v),
                                    __builtin_bit_cast(int, v), CTRL, 0xF, 0xF, true));
}
template <int J>
__device__ __forceinline__ float xch_f(float v) {
    if constexpr (J == 1) return dpp_f<DPP_X1>(v);
    else if constexpr (J == 2) return dpp_f<DPP_X2>(v);
    else if constexpr (J == 8) return dpp_f<DPP_X8>(v);
    else return __shfl_xor(v, J, 64);
}
template <int J>
__device__ __forceinline__ int xch_i(int v) {
    if constexpr (J == 1) return dpp_i<DPP_X1>(v);
    else if constexpr (J == 2) return dpp_i<DPP_X2>(v);
    else if constexpr (J == 8) return dpp_i<DPP_X8>(v);
    else return __shfl_xor(v, J, 64);
}

// all-DPP wave64 max-reduce (LLVM AtomicOptimizer pattern) + readlane broadcast.
// Max of DISTINCT u32 keys is association-free -> same winner as any reduce order.
// row_shr with bound_ctrl=1 shifts in 0 (never wins; real keys are nonzero).
__device__ __forceinline__ unsigned wave_max_key(unsigned k) {
    unsigned t;
    t = (unsigned)__builtin_amdgcn_update_dpp((int)k, (int)k, 0x111, 0xF, 0xF, true);  // row_shr:1
    k = t > k ? t : k;
    t = (unsigned)__builtin_amdgcn_update_dpp((int)k, (int)k, 0x112, 0xF, 0xF, true);  // row_shr:2
    k = t > k ? t : k;
    t = (unsigned)__builtin_amdgcn_update_dpp((int)k, (int)k, 0x114, 0xF, 0xF, true);  // row_shr:4
    k = t > k ? t : k;
    t = (unsigned)__builtin_amdgcn_update_dpp((int)k, (int)k, 0x118, 0xF, 0xF, true);  // row_shr:8
    k = t > k ? t : k;
    t = (unsigned)__builtin_amdgcn_update_dpp((int)k, (int)k, 0x142, 0xA, 0xF, false); // row_bcast:15 -> rows 1,3
    k = t > k ? t : k;
    t = (unsigned)__builtin_amdgcn_update_dpp((int)k, (int)k, 0x143, 0xC, 0xF, false); // row_bcast:31 -> rows 2,3
    k = t > k ? t : k;
    return (unsigned)__builtin_amdgcn_readlane((int)k, 63);  // lane 63 = global max; uniform
}

// ---------------- fp32 -> f16 hi (K padded to 416) + row sum-of-squares ----------------
__global__ __launch_bounds__(256) void k_split_hi(const float* __restrict__ in,
                                                  unsigned short* __restrict__ hi,
                                                  float* __restrict__ ss, int rows) {
    int row  = blockIdx.x * 4 + (threadIdx.x >> 6);
    int lane = threadIdx.x & 63;
    if (row >= rows) return;
    const float* src = in + (size_t)row * EDIM;
    unsigned short* ph = hi + (size_t)row * KPAD;
    float s = 0.f;
    #pragma unroll
    for (int q = 0; q < 2; ++q) {
        int c4 = lane + q * 64;
        if (c4 < KPAD / 4) {
            int k = c4 * 4;
            float4 v = make_float4(0.f, 0.f, 0.f, 0.f);
            if (k < EDIM) v = *(const float4*)(src + k);
            float va[4] = {v.x, v.y, v.z, v.w};
            unsigned short ha[4];
            #pragma unroll
            for (int t = 0; t < 4; ++t) {
                float f = va[t];
                _Float16 h = (_Float16)f;
                ha[t] = __builtin_bit_cast(unsigned short, h);
                s = fmaf(f, f, s);
            }
            ushort4 H; H.x = ha[0]; H.y = ha[1]; H.z = ha[2]; H.w = ha[3];
            *(ushort4*)(ph + k) = H;
        }
    }
    #pragma unroll
    for (int o = 32; o; o >>= 1) s += __shfl_xor(s, o, 64);
    if (lane == 0) ss[row] = s;
}

// ---------------- per-group embedding sums: Sg = sum emb (exact), SgH = sum fl16(emb) ----------------
__global__ __launch_bounds__(448) void k_groupsum(const float* __restrict__ emb,
                                                  const unsigned short* __restrict__ ehi,
                                                  float* __restrict__ Sg,
                                                  float* __restrict__ SgH) {
    const int g = blockIdx.x;
    const int t = threadIdx.x;          // 0..447
    float se = 0.f, sh = 0.f;
    if (t < EDIM) {
        for (int j = 0; j < CPG; ++j) {
            se += emb[(size_t)(g * CPG + j) * EDIM + t];
            _Float16 h = __builtin_bit_cast(_Float16, ehi[(size_t)(g * CPG + j) * KPAD + t]);
            sh += (float)h;
        }
    }
    Sg[g * SGS + t]  = se;
    SgH[g * SGS + t] = sh;
}

// ---------------- 1-pass f16 MFMA distance GEMM, 2-phase pipelined ----------------
// Sync points (R7/R9 lessons): fused asm waitcnt+barrier with "memory" clobber;
// end barrier carries lgkmcnt(0) so LDS reads complete before buffer reuse.
__global__ __launch_bounds__(256, 4) void k_dist1(
    const unsigned short* __restrict__ xhi, const unsigned short* __restrict__ ehi,
    const float* __restrict__ xx, const float* __restrict__ ee,
    float* __restrict__ enc, float* __restrict__ gsum) {
    __shared__ __attribute__((aligned(16))) _Float16 Ah[2][128][BK];
    __shared__ __attribute__((aligned(16))) _Float16 Bh[2][128][BK];

    const int wg    = blockIdx.x;
    const int xcd   = wg & 7;
    const int local = wg >> 3;            // 0..511
    const int mx    = xcd * 32 + (local & 31);
    const int ny    = local >> 5;         // 0..15
    const int m0    = mx * 128;
    const int n0    = ny * 128;

    const int tid  = threadIdx.x;
    const int lane = tid & 63, wid = tid >> 6;
    const int wr = (wid >> 1) * 64, wc = (wid & 1) * 64;
    const int lr = lane & 15, ko = lane >> 4;

    auto stage = [&](int b, int kt) {
        const int k0 = kt * BK;
        #pragma unroll
        for (int q = 0; q < 2; ++q) {
            int cc = q * 256 + tid;       // 0..511 chunks of 16B per array
            int rw = cc >> 2, kc = cc & 3;
            size_t goA = (size_t)(m0 + rw) * KPAD + k0 + kc * 8;
            size_t goB = (size_t)(n0 + rw) * KPAD + k0 + kc * 8;
            int loff = (cc >> 6) * 1024;  // wave-uniform LDS base
            gld_lds16(xhi + goA, (char*)&Ah[b][0][0] + loff);
            gld_lds16(ehi + goB, (char*)&Bh[b][0][0] + loff);
        }
    };

    f32x4 acc[4][4];
    #pragma unroll
    for (int i = 0; i < 4; ++i)
        #pragma unroll
        for (int j = 0; j < 4; ++j) { f32x4 z = {0.f, 0.f, 0.f, 0.f}; acc[i][j] = z; }

    stage(0, 0);
    for (int kt = 0; kt < NKT; ++kt) {
        const int cur = kt & 1;
        if (kt + 1 < NKT) {
            stage(cur ^ 1, kt + 1);       // next tile's 4 loads in flight
            asm volatile("s_waitcnt vmcnt(4)\n\ts_barrier" ::: "memory");
        } else {
            asm volatile("s_waitcnt vmcnt(0)\n\ts_barrier" ::: "memory");
        }

        f16x8 a_h[4];
        #pragma unroll
        for (int i = 0; i < 4; ++i)
            a_h[i] = *(const f16x8*)&Ah[cur][wr + i * 16 + lr][ko * 8];
        #pragma unroll
        for (int j = 0; j < 4; ++j) {
            f16x8 b_h = *(const f16x8*)&Bh[cur][wc + j * 16 + lr][ko * 8];
            #pragma unroll
            for (int i = 0; i < 4; ++i)
                acc[i][j] = __builtin_amdgcn_mfma_f32_16x16x32_f16(a_h[i], b_h, acc[i][j], 0, 0, 0);
        }
        asm volatile("s_waitcnt lgkmcnt(0)\n\ts_barrier" ::: "memory");
    }

    #pragma unroll
    for (int i = 0; i < 4; ++i) {
        #pragma unroll
        for (int r = 0; r < 4; ++r) {
            int row = m0 + wr + i * 16 + ko * 4 + r;
            float xm = xx[row];
            float rs = 0.f;
            #pragma unroll
            for (int j = 0; j < 4; ++j) {
                int col = n0 + wc + j * 16 + lr;
                float dd = fmaf(-2.f, acc[i][j][r], xm + ee[col]);
                rs += dd;
                // v_rcp_f32 (1-ulp approx) instead of IEEE divide (~10-inst seq):
                // enc perturbed ~1e-10 abs; containment margins are 4e-6-class.
                enc[(size_t)row * N_CLS + col] = __builtin_amdgcn_rcpf(dd);
            }
            rs += dpp_f<DPP_X1>(rs);
            rs += dpp_f<DPP_X2>(rs);
            rs += __shfl_xor(rs, 4, 64);
            rs += dpp_f<DPP_X8>(rs);
            if (lr == 0)
                gsum[(size_t)row * NPART + ny * 2 + (wc >> 6)] = rs;
        }
    }
}

// ---------------- per-row select: DPP-max Phase A + float4 Phase D ----------------
__global__ __launch_bounds__(256) void k_select7(const float* __restrict__ x,
                                                 const float* __restrict__ emb,
                                                 const float* __restrict__ enc,
                                                 const float* __restrict__ gsum,
                                                 const float* __restrict__ Sg,
                                                 const float* __restrict__ SgH,
                                                 const float* __restrict__ xx,
                                                 const float* __restrict__ ee,
                                                 float* __restrict__ out0,
                                                 float* __restrict__ rmse,
                                                 unsigned int* __restrict__ hist) {
    const int wave = threadIdx.x >> 6;
    const int lane = threadIdx.x & 63;
    const int m = blockIdx.x * 4 + wave;

    const float* xrg = x + (size_t)m * EDIM;
    float xr[7], xh[7];
    #pragma unroll
    for (int k = 0; k < 7; ++k) {
        int d = lane + 64 * k;
        float f = (d < EDIM) ? xrg[d] : 0.f;
        xr[k] = f;
        xh[k] = (float)(_Float16)f;
    }
    const float xm = xx[m];

    // ---- group scores (numerics IDENTICAL to R8/R10-passing version) ----
    float aD[NGRP];
    #pragma unroll
    for (int g = 0; g < NGRP; ++g) aD[g] = 0.f;
    #pragma unroll
    for (int k = 0; k < 7; ++k) {
        int d = lane + 64 * k;   // < 448 always; pads are zero
        #pragma unroll
        for (int g = 0; g < NGRP; ++g) {
            aD[g] = fmaf(xr[k], Sg[g * SGS + d], aD[g]);
            aD[g] = fmaf(-xh[k], SgH[g * SGS + d], aD[g]);
        }
    }
    #pragma unroll
    for (int g = 0; g < NGRP; ++g) {
        aD[g] += dpp_f<DPP_X8>(aD[g]);
        aD[g] += __shfl_xor(aD[g], 16, 64);
        aD[g] += __shfl_xor(aD[g], 32, 64);
    }
    const int myg = (lane >> 3) & 7;
    float s = aD[0];
    s = (myg == 1) ? aD[1] : s;
    s = (myg == 2) ? aD[2] : s;
    s = (myg == 3) ? aD[3] : s;
    s = (myg == 4) ? aD[4] : s;
    s = (myg == 5) ? aD[5] : s;
    s = (myg == 6) ? aD[6] : s;
    s = (myg == 7) ? aD[7] : s;
    s += dpp_f<DPP_X1>(s);
    s += dpp_f<DPP_X2>(s);
    s += __shfl_xor(s, 4, 64);
    const float* gs = gsum + (size_t)m * NPART;
    float base = gs[myg * 4 + 0] + gs[myg * 4 + 1] + gs[myg * 4 + 2] + gs[myg * 4 + 3];
    float sc = fmaf(-2.f, s, base);
    int bg = myg; float bv = sc;
    {
        float ov = dpp_f<DPP_X8>(bv); int og = dpp_i<DPP_X8>(bg);
        if (ov < bv || (ov == bv && og < bg)) { bv = ov; bg = og; }
    }
    #pragma unroll
    for (int o = 16; o < 64; o <<= 1) {
        float ov = __shfl_xor(bv, o, 64);
        int   og = __shfl_xor(bg, o, 64);
        if (ov < bv || (ov == bv && og < bg)) { bv = ov; bg = og; }
    }
    const int j0 = bg * CPG;

    // ---- Phase A: top-16 via packed keys; winner per round by all-DPP max reduce.
    // Same distinct keys as R10 -> bit-identical candidate set, ~no DS latency chain.
    const float* pr = enc + (size_t)m * N_CLS + j0;
    float4 pv4 = *(const float4*)(pr + lane * 4);
    unsigned key0 = (__float_as_uint(pv4.x) & 0xFFFFFF00u) | (255u - (unsigned)(lane * 4 + 0));
    unsigned key1 = (__float_as_uint(pv4.y) & 0xFFFFFF00u) | (255u - (unsigned)(lane * 4 + 1));
    unsigned key2 = (__float_as_uint(pv4.z) & 0xFFFFFF00u) | (255u - (unsigned)(lane * 4 + 2));
    unsigned key3 = (__float_as_uint(pv4.w) & 0xFFFFFF00u) | (255u - (unsigned)(lane * 4 + 3));

    unsigned candKey = 0;
    #pragma unroll
    for (int t = 0; t < NCAND; ++t) {
        unsigned a01 = key0 > key1 ? key0 : key1;
        unsigned a23 = key2 > key3 ? key2 : key3;
        unsigned mk  = a01 > a23 ? a01 : a23;
        unsigned win = wave_max_key(mk);           // uniform
        if (lane == t) candKey = win;
        unsigned widx = 255u - (win & 0xFFu);
        if ((widx >> 2) == (unsigned)lane) {
            unsigned slot = widx & 3u;
            key0 = (slot == 0u) ? 0u : key0;
            key1 = (slot == 1u) ? 0u : key1;
            key2 = (slot == 2u) ? 0u : key2;
            key3 = (slot == 3u) ? 0u : key3;
        }
    }
    int cand = 255 - (int)(candKey & 0xFFu);   // valid on lanes 0..15

    // ---- Phase B: exact fp32 refine, 4 lanes per candidate (unchanged) ----
    int cj = __shfl(cand, lane >> 2, 64);
    int jg = j0 + cj;
    const float4* er4 = (const float4*)(emb + (size_t)jg * EDIM);
    const float4* xs4 = (const float4*)xrg;
    float a = 0.f;
    #pragma unroll
    for (int q = 0; q < 25; ++q) {
        int idx = (lane & 3) + 4 * q;              // 0..99
        float4 e = er4[idx];
        float4 xv = xs4[idx];
        a = fmaf(xv.x, e.x, a);
        a = fmaf(xv.y, e.y, a);
        a = fmaf(xv.z, e.z, a);
        a = fmaf(xv.w, e.w, a);
    }
    a += dpp_f<DPP_X1>(a);
    a += dpp_f<DPP_X2>(a);
    float dd = fmaf(-2.f, a, xm + ee[jg]);
    float pvq = 1.0f / dd;
    float pcur = __shfl(pvq, (lane & 15) * 4, 64);
    int   ccur = __shfl(cand, lane & 15, 64);

    // ---- Phase C: bitonic sort-16 desc by (pv, -cidx) (unchanged) ----
    const int l16 = lane & 15;
#define BSTEP(K_, J_) { \
        float opv = xch_f<J_>(pcur); int occ = xch_i<J_>(ccur); \
        bool amLow     = (l16 & (J_)) == 0; \
        bool blockDesc = (l16 & (K_)) == 0; \
        bool iGreater  = (pcur > opv) || (pcur == opv && ccur < occ); \
        bool keep = (amLow == blockDesc) ? iGreater : !iGreater; \
        if (!keep) { pcur = opv; ccur = occ; } }
    BSTEP(2, 1)
    BSTEP(4, 2) BSTEP(4, 1)
    BSTEP(8, 4) BSTEP(8, 2) BSTEP(8, 1)
    BSTEP(16, 8) BSTEP(16, 4) BSTEP(16, 2) BSTEP(16, 1)
#undef BSTEP

    float ps = (l16 < NS) ? pcur : 0.f;
    ps += dpp_f<DPP_X1>(ps);
    ps += dpp_f<DPP_X2>(ps);
    ps += __shfl_xor(ps, 4, 64);
    ps += dpp_f<DPP_X8>(ps);
    float wn = fmaxf(ps, 1e-12f);

    if (lane == 0) atomicAdd(&hist[j0 + ccur], 1u);   // lane 0 = top-1

    // ---- Phase D: float4 gather-sum + straight-through + mse ----
    // Per-element FMA chain over t unchanged -> out0 values bit-identical to R10;
    // only the lane<->element partition changes (3x fewer loads/stores).
    float wt[NS]; int gt[NS];
    #pragma unroll
    for (int t = 0; t < NS; ++t) {
        wt[t] = __shfl(pcur, t, 16) / wn;
        gt[t] = j0 + __shfl(ccur, t, 16);
    }
    float4* orow4 = (float4*)(out0 + (size_t)m * EDIM);
    float sq = 0.f;
    #pragma unroll
    for (int h = 0; h < 2; ++h) {
        int gidx = lane + h * 64;                  // float4 granule 0..99
        if (gidx < EDIM / 4) {
            float4 xv = xs4[gidx];
            float ox = 0.f, oy = 0.f, oz = 0.f, ow = 0.f;
            #pragma unroll
            for (int t = 0; t < NS; ++t) {
                float4 e = ((const float4*)(emb + (size_t)gt[t] * EDIM))[gidx];
                ox = fmaf(wt[t], e.x, ox);
                oy = fmaf(wt[t], e.y, oy);
                oz = fmaf(wt[t], e.z, oz);
                ow = fmaf(wt[t], e.w, ow);
            }
            float dx = xv.x - ox, dy = xv.y - oy, dz = xv.z - oz, dw = xv.w - ow;
            sq = fmaf(dx, dx, sq);
            sq = fmaf(dy, dy, sq);
            sq = fmaf(dz, dz, sq);
            sq = fmaf(dw, dw, sq);
            float4 st;
            st.x = (ox - xv.x) + xv.x;
            st.y = (oy - xv.y) + xv.y;
            st.z = (oz - xv.z) + xv.z;
            st.w = (ow - xv.w) + xv.w;
            orow4[gidx] = st;
        }
    }
    sq += dpp_f<DPP_X1>(sq);
    sq += dpp_f<DPP_X2>(sq);
    sq += __shfl_xor(sq, 4, 64);
    sq += dpp_f<DPP_X8>(sq);
    sq += __shfl_xor(sq, 16, 64);
    sq += __shfl_xor(sq, 32, 64);
    if (lane == 0) rmse[m] = sq;
}

// ---------------- final deterministic reduction: loss + entropy ----------------
__global__ __launch_bounds__(1024) void k_final(const float* __restrict__ rmse,
                                                const unsigned int* __restrict__ hist,
                                                float* __restrict__ loss_out,
                                                float* __restrict__ ent_out) {
    __shared__ float red[1024];
    const int t = threadIdx.x;

    float s = 0.f;
    for (int i = t; i < M_ROWS; i += 1024) s += rmse[i];
    red[t] = s; __syncthreads();
    for (int off = 512; off; off >>= 1) {
        if (t < off) red[t] += red[t + off];
        __syncthreads();
    }
    if (t == 0) {
        float q = red[0] / 13107200.0f;
        loss_out[0] = q + 0.25f * q;
    }
    __syncthreads();

    float e = 0.f;
    for (int i = t; i < N_CLS; i += 1024) {
        unsigned int h = hist[i];
        if (h > 0) {
            float prb = (float)h / 32768.0f;
            e -= prb * logf(prb);
        }
    }
    red[t] = e; __syncthreads();
    for (int off = 512; off; off >>= 1) {
        if (t < off) red[t] += red[t + off];
        __syncthreads();
    }
    if (t == 0) ent_out[0] = red[0];
}

extern "C" void kernel_launch(void* const* d_in, const int* in_sizes, int n_in,
                              void* d_out, int out_size, void* d_ws, size_t ws_size,
                              hipStream_t stream) {
    const float* x   = (const float*)d_in[0];   // [32768, 400]
    const float* emb = (const float*)d_in[1];   // [2048, 400]

    float* out      = (float*)d_out;
    float* loss_out = out;
    float* out0     = out + 1;
    float* ent_out  = out + 1 + M_ROWS * EDIM;
    float* enc      = out + 2 + M_ROWS * EDIM;

    float* ws   = (float*)d_ws;
    float* ee   = ws;                                   // [2048]
    float* xx   = ee + N_CLS;                           // [32768]
    float* Sg   = xx + M_ROWS;                          // [8][448]
    float* SgH  = Sg + NGRP * SGS;                      // [8][448]
    float* gsum = SgH + NGRP * SGS;                     // [32768][32]
    float* rmse = gsum + (size_t)M_ROWS * NPART;        // [32768]
    unsigned int* hist = (unsigned int*)(rmse + M_ROWS);// [2048]
    float* fend = rmse + M_ROWS + N_CLS;

    unsigned short* xhi = (unsigned short*)fend;        // [32768][416]
    unsigned short* ehi = xhi + (size_t)M_ROWS * KPAD;  // [2048][416]

    hipMemsetAsync(hist, 0, N_CLS * sizeof(unsigned int), stream);

    k_split_hi<<<M_ROWS / 4, 256, 0, stream>>>(x, xhi, xx, M_ROWS);
    k_split_hi<<<N_CLS / 4, 256, 0, stream>>>(emb, ehi, ee, N_CLS);
    k_groupsum<<<NGRP, 448, 0, stream>>>(emb, ehi, Sg, SgH);

    k_dist1<<<(M_ROWS / 128) * (N_CLS / 128), 256, 0, stream>>>(xhi, ehi, xx, ee, enc, gsum);

    k_select7<<<M_ROWS / 4, 256, 0, stream>>>(x, emb, enc, gsum, Sg, SgH, xx, ee,
                                              out0, rmse, hist);

    k_final<<<1, 1024, 0, stream>>>(rmse, hist, loss_out, ent_out);
}